// Round 4
// baseline (3540.010 us; speedup 1.0000x reference)
//
#include <hip/hip_runtime.h>
#include <hip/hip_bf16.h>

typedef unsigned short u16;

// ---------- helpers ----------
__device__ __forceinline__ float b2f(u16 u) { return __uint_as_float(((unsigned)u) << 16); }
__device__ __forceinline__ u16 f2b(float f) {
    unsigned u = __float_as_uint(f);
    unsigned r = 0x7FFFu + ((u >> 16) & 1u);
    return (u16)((u + r) >> 16);
}
__device__ __forceinline__ float silu_f(float x) { return x / (1.0f + expf(-x)); }

// ---------- constants ----------
// DIM=1024, HID=2048, QK=128, G=256, NG=16, B=4, ROWS=16384
// I/O dtype: FP32 (per reference setup_inputs). Intermediates: bf16 in ws.
// heads: 0=quad_q 1=lin_q 2=quad_k 3=lin_k

// ---------- LayerNorm: fp32 in -> bf16 out ----------
__global__ __launch_bounds__(256) void ln_kernel(const float* __restrict__ x,
                                                 const float* __restrict__ w,
                                                 const float* __restrict__ bsh,
                                                 u16* __restrict__ out) {
    int row = blockIdx.x, t = threadIdx.x;
    const float* xr = x + (size_t)row * 1024;
    float4 u = *reinterpret_cast<const float4*>(xr + t * 4);
    float s = u.x + u.y + u.z + u.w;
    float s2 = u.x * u.x + u.y * u.y + u.z * u.z + u.w * u.w;
#pragma unroll
    for (int o = 32; o; o >>= 1) {
        s += __shfl_down(s, o, 64);
        s2 += __shfl_down(s2, o, 64);
    }
    __shared__ float rs[4], rs2[4];
    int wid = t >> 6;
    if ((t & 63) == 0) { rs[wid] = s; rs2[wid] = s2; }
    __syncthreads();
    float S = rs[0] + rs[1] + rs[2] + rs[3];
    float S2 = rs2[0] + rs2[1] + rs2[2] + rs2[3];
    float mu = S * (1.0f / 1024.0f);
    float var = S2 * (1.0f / 1024.0f) - mu * mu;
    float rinv = rsqrtf(var + 1e-5f);
    float4 uw = *reinterpret_cast<const float4*>(w + t * 4);
    float4 ub = *reinterpret_cast<const float4*>(bsh + t * 4);
    ushort4 o;
    o.x = f2b((u.x - mu) * rinv * uw.x + ub.x);
    o.y = f2b((u.y - mu) * rinv * uw.y + ub.y);
    o.z = f2b((u.z - mu) * rinv * uw.z + ub.z);
    o.w = f2b((u.w - mu) * rinv * uw.w + ub.w);
    *reinterpret_cast<ushort4*>(out + (size_t)row * 1024 + t * 4) = o;
}

// ---------- tiled GEMM: C = epilogue(A[M,K](lda,bf16) @ B[K,N](fp32) + bias) ----------
// MODE 0: silu(acc + bias) -> bf16 C      MODE 1: acc + bias + resid -> fp32 C
template <int MODE>
__global__ __launch_bounds__(256) void gemm64(const u16* __restrict__ A, int lda,
                                              const float* __restrict__ Bm,
                                              const float* __restrict__ bias,
                                              const float* __restrict__ resid,
                                              void* __restrict__ Cv,
                                              int M, int Nn, int K) {
    __shared__ float As[16][64];
    __shared__ float Bs[16][64];
    const int t = threadIdx.x;
    const int tx = t & 15, ty = t >> 4;
    const int m0 = blockIdx.y * 64, n0 = blockIdx.x * 64;
    float acc[4][4] = {};

    const int ar = t >> 2, ac = (t & 3) * 4;
    const int br = t >> 4, bc = (t & 15) * 4;
    const u16* aptr = A + (size_t)(m0 + ar) * lda + ac;
    const float* bptr = Bm + (size_t)br * Nn + n0 + bc;

    for (int k0 = 0; k0 < K; k0 += 16) {
        ushort4 ua = *reinterpret_cast<const ushort4*>(aptr + k0);
        float4 ub = *reinterpret_cast<const float4*>(bptr + (size_t)k0 * Nn);
        As[ac + 0][ar] = b2f(ua.x);
        As[ac + 1][ar] = b2f(ua.y);
        As[ac + 2][ar] = b2f(ua.z);
        As[ac + 3][ar] = b2f(ua.w);
        Bs[br][bc + 0] = ub.x;
        Bs[br][bc + 1] = ub.y;
        Bs[br][bc + 2] = ub.z;
        Bs[br][bc + 3] = ub.w;
        __syncthreads();
#pragma unroll
        for (int kk = 0; kk < 16; ++kk) {
            float4 a = *reinterpret_cast<const float4*>(&As[kk][ty * 4]);
            float4 b = *reinterpret_cast<const float4*>(&Bs[kk][tx * 4]);
            acc[0][0] += a.x * b.x; acc[0][1] += a.x * b.y; acc[0][2] += a.x * b.z; acc[0][3] += a.x * b.w;
            acc[1][0] += a.y * b.x; acc[1][1] += a.y * b.y; acc[1][2] += a.y * b.z; acc[1][3] += a.y * b.w;
            acc[2][0] += a.z * b.x; acc[2][1] += a.z * b.y; acc[2][2] += a.z * b.z; acc[2][3] += a.z * b.w;
            acc[3][0] += a.w * b.x; acc[3][1] += a.w * b.y; acc[3][2] += a.w * b.z; acc[3][3] += a.w * b.w;
        }
        __syncthreads();
    }
#pragma unroll
    for (int i = 0; i < 4; ++i) {
        int m = m0 + ty * 4 + i;
#pragma unroll
        for (int j = 0; j < 4; ++j) {
            int n = n0 + tx * 4 + j;
            float v = acc[i][j] + bias[n];
            if (MODE == 0) {
                v = silu_f(v);
                ((u16*)Cv)[(size_t)m * Nn + n] = f2b(v);
            } else {
                v += resid[(size_t)m * Nn + n];
                ((float*)Cv)[(size_t)m * Nn + n] = v;
            }
        }
    }
}

// ---------- per-group kv: kv[bg][d][e] = (1/256) * sum_n lin_k[n][d] * v[n][e] ----------
__global__ __launch_bounds__(256) void kv_kernel(const u16* __restrict__ qk,
                                                 const u16* __restrict__ hv,
                                                 const float* __restrict__ qk_w,
                                                 const float* __restrict__ qk_b,
                                                 u16* __restrict__ kvbuf) {
    __shared__ float ks[16][128];
    __shared__ float vs[16][64];
    __shared__ float kw[128], kb[128];
    int t = threadIdx.x;
    int bg = blockIdx.x, et = blockIdx.y;
    if (t < 128) {
        kw[t] = qk_w[3 * 128 + t];
        kb[t] = qk_b[3 * 128 + t];
    }
    __syncthreads();
    int d0 = (t >> 3) * 4;
    int e0 = (t & 7) * 8;
    float acc[4][8] = {};
    int rowbase = bg * 256;
    for (int n0 = 0; n0 < 256; n0 += 16) {
        {
            int r = t >> 4, c = (t & 15) * 8;
            const u16* p = qk + (size_t)(rowbase + n0 + r) * 128 + c;
#pragma unroll
            for (int q = 0; q < 2; ++q) {
                ushort4 u = *reinterpret_cast<const ushort4*>(p + q * 4);
                int cc = c + q * 4;
                ks[r][cc + 0] = b2f(u.x) * kw[cc + 0] + kb[cc + 0];
                ks[r][cc + 1] = b2f(u.y) * kw[cc + 1] + kb[cc + 1];
                ks[r][cc + 2] = b2f(u.z) * kw[cc + 2] + kb[cc + 2];
                ks[r][cc + 3] = b2f(u.w) * kw[cc + 3] + kb[cc + 3];
            }
        }
        {
            int r = t >> 4, c = (t & 15) * 4;
            const u16* p = hv + (size_t)(rowbase + n0 + r) * 4096 + et * 64 + c;
            ushort4 u = *reinterpret_cast<const ushort4*>(p);
            vs[r][c + 0] = b2f(u.x);
            vs[r][c + 1] = b2f(u.y);
            vs[r][c + 2] = b2f(u.z);
            vs[r][c + 3] = b2f(u.w);
        }
        __syncthreads();
#pragma unroll
        for (int kk = 0; kk < 16; ++kk) {
            float4 kf = *reinterpret_cast<const float4*>(&ks[kk][d0]);
            float4 va = *reinterpret_cast<const float4*>(&vs[kk][e0]);
            float4 vb = *reinterpret_cast<const float4*>(&vs[kk][e0 + 4]);
            float kfv[4] = {kf.x, kf.y, kf.z, kf.w};
            float vv[8] = {va.x, va.y, va.z, va.w, vb.x, vb.y, vb.z, vb.w};
#pragma unroll
            for (int i = 0; i < 4; ++i)
#pragma unroll
                for (int j = 0; j < 8; ++j) acc[i][j] += kfv[i] * vv[j];
        }
        __syncthreads();
    }
#pragma unroll
    for (int i = 0; i < 4; ++i)
#pragma unroll
        for (int j = 0; j < 8; ++j) {
            size_t idx = ((size_t)bg * 128 + d0 + i) * 2048 + et * 64 + e0 + j;
            kvbuf[idx] = f2b(acc[i][j] * (1.0f / 256.0f));
        }
}

// ---------- shifted cumsum over groups (in-place) ----------
__global__ __launch_bounds__(256) void prefix_kernel(u16* __restrict__ kvbuf) {
    size_t tid = (size_t)blockIdx.x * 256 + threadIdx.x;  // 1,048,576
    int e = (int)(tid & 2047);
    int d = (int)((tid >> 11) & 127);
    int b = (int)(tid >> 18);
    size_t base = ((size_t)b * 16 * 128 + d) * 2048 + e;
    const size_t gs = 128 * 2048;
    float vals[16];
#pragma unroll
    for (int g = 0; g < 16; ++g) vals[g] = b2f(kvbuf[base + (size_t)g * gs]);
    float s = 0.0f;
#pragma unroll
    for (int g = 0; g < 16; ++g) {
        kvbuf[base + (size_t)g * gs] = f2b(s);
        s += vals[g];
    }
}

// ---------- attention: per (group, 16-row i-tile) ----------
// Writes the gated output IN PLACE into the gate half of hv (cols 2048..4095).
__global__ __launch_bounds__(256) void attn_kernel(const u16* __restrict__ qk,
                                                   u16* __restrict__ hv,
                                                   const u16* __restrict__ kvbuf,
                                                   const float* __restrict__ qk_w,
                                                   const float* __restrict__ qk_b,
                                                   const float* __restrict__ rel_table) {
    __shared__ float qq[16][128];
    __shared__ float lq[16][128];
    __shared__ float attnS[16][256];
    __shared__ float stage[4096];
    __shared__ float biasn[256];
    __shared__ float w0[128], b0[128], w1[128], b1[128], w2[128], b2v[128];
    int t = threadIdx.x;
    int bg = blockIdx.x, it = blockIdx.y;

    if (t < 128) {
        w0[t] = qk_w[t];        b0[t] = qk_b[t];
        w1[t] = qk_w[128 + t];  b1[t] = qk_b[128 + t];
        w2[t] = qk_w[256 + t];  b2v[t] = qk_b[256 + t];
    }
    {
        int n = t;
        int bucket;
        if (n < 16) bucket = n;
        else {
            float v = logf((float)n / 16.0f) / 2.0794415416798357f * 16.0f;
            int vl = 16 + (int)v;
            bucket = vl > 31 ? 31 : vl;
        }
        biasn[n] = rel_table[bucket] * 11.313708498984761f;
    }
    __syncthreads();

    // stage quad_q / lin_q for this i-tile
    {
        int r = t >> 4, c = (t & 15) * 8;
        const u16* p = qk + (size_t)(bg * 256 + it * 16 + r) * 128 + c;
#pragma unroll
        for (int q = 0; q < 2; ++q) {
            ushort4 u = *reinterpret_cast<const ushort4*>(p + q * 4);
            float f[4] = {b2f(u.x), b2f(u.y), b2f(u.z), b2f(u.w)};
#pragma unroll
            for (int k = 0; k < 4; ++k) {
                int cc = c + q * 4 + k;
                qq[r][cc] = f[k] * w0[cc] + b0[cc];
                lq[r][cc] = f[k] * w1[cc] + b1[cc];
            }
        }
    }
    __syncthreads();

    int jmax = it * 16 + 15;

    // Phase A: attn scores
    for (int j0 = 0; j0 <= jmax; j0 += 32) {
        {
            int r = t >> 3, c = (t & 7) * 16;
            const u16* p = qk + (size_t)(bg * 256 + j0 + r) * 128 + c;
#pragma unroll
            for (int q = 0; q < 4; ++q) {
                ushort4 u = *reinterpret_cast<const ushort4*>(p + q * 4);
                float f[4] = {b2f(u.x), b2f(u.y), b2f(u.z), b2f(u.w)};
#pragma unroll
                for (int k = 0; k < 4; ++k) {
                    int cc = c + q * 4 + k;
                    stage[r * 128 + cc] = f[k] * w2[cc] + b2v[cc];
                }
            }
        }
        __syncthreads();
        int i = t >> 4;
        int gi = it * 16 + i;
#pragma unroll
        for (int u2 = 0; u2 < 2; ++u2) {
            int j = (t & 15) * 2 + u2;
            int gj = j0 + j;
            float dot = 0.0f;
            const float* qrow = &qq[i][0];
            const float* krow = &stage[j * 128];
#pragma unroll
            for (int c = 0; c < 128; c += 4) {
                float4 qa = *reinterpret_cast<const float4*>(qrow + c);
                float4 ka = *reinterpret_cast<const float4*>(krow + c);
                dot += qa.x * ka.x + qa.y * ka.y + qa.z * ka.z + qa.w * ka.w;
            }
            float aval = 0.0f;
            if (gj <= gi) {
                float sv = dot * (1.0f / 256.0f) + biasn[gi - gj];
                sv = fmaxf(sv, 0.0f);
                aval = sv * sv;
            }
            attnS[i][j0 + j] = aval;
        }
        __syncthreads();  // stage[] reused next iter / Phase B
    }

    // Phase B: out = attn @ v + lin_q @ kvpref, times gate
    int i2 = t >> 5;
    int e8 = (t & 31) * 8;
    size_t rowg = (size_t)bg * 256 + it * 16;
    for (int ec = 0; ec < 2048; ec += 256) {
        float acc0[8] = {};
        float acc1[8] = {};
        // quadratic part
        for (int j0 = 0; j0 <= jmax; j0 += 16) {
            {
                int r = t >> 4, c = (t & 15) * 16;
                const u16* p = hv + (size_t)(bg * 256 + j0 + r) * 4096 + ec + c;
#pragma unroll
                for (int q = 0; q < 4; ++q) {
                    ushort4 u = *reinterpret_cast<const ushort4*>(p + q * 4);
                    stage[r * 256 + c + q * 4 + 0] = b2f(u.x);
                    stage[r * 256 + c + q * 4 + 1] = b2f(u.y);
                    stage[r * 256 + c + q * 4 + 2] = b2f(u.z);
                    stage[r * 256 + c + q * 4 + 3] = b2f(u.w);
                }
            }
            __syncthreads();
#pragma unroll
            for (int j = 0; j < 16; ++j) {
                float a0 = attnS[i2][j0 + j];
                float a1 = attnS[i2 + 8][j0 + j];
                const float* vr = &stage[j * 256 + e8];
                float4 p0 = *reinterpret_cast<const float4*>(vr);
                float4 p1 = *reinterpret_cast<const float4*>(vr + 4);
                float vv[8] = {p0.x, p0.y, p0.z, p0.w, p1.x, p1.y, p1.z, p1.w};
#pragma unroll
                for (int q = 0; q < 8; ++q) {
                    acc0[q] += a0 * vv[q];
                    acc1[q] += a1 * vv[q];
                }
            }
            __syncthreads();
        }
        // linear part
        for (int d0 = 0; d0 < 128; d0 += 16) {
            {
                int r = t >> 4, c = (t & 15) * 16;
                const u16* p = kvbuf + ((size_t)bg * 128 + d0 + r) * 2048 + ec + c;
#pragma unroll
                for (int q = 0; q < 4; ++q) {
                    ushort4 u = *reinterpret_cast<const ushort4*>(p + q * 4);
                    stage[r * 256 + c + q * 4 + 0] = b2f(u.x);
                    stage[r * 256 + c + q * 4 + 1] = b2f(u.y);
                    stage[r * 256 + c + q * 4 + 2] = b2f(u.z);
                    stage[r * 256 + c + q * 4 + 3] = b2f(u.w);
                }
            }
            __syncthreads();
#pragma unroll
            for (int j = 0; j < 16; ++j) {
                float a0 = lq[i2][d0 + j];
                float a1 = lq[i2 + 8][d0 + j];
                const float* vr = &stage[j * 256 + e8];
                float4 p0 = *reinterpret_cast<const float4*>(vr);
                float4 p1 = *reinterpret_cast<const float4*>(vr + 4);
                float vv[8] = {p0.x, p0.y, p0.z, p0.w, p1.x, p1.y, p1.z, p1.w};
#pragma unroll
                for (int q = 0; q < 8; ++q) {
                    acc0[q] += a0 * vv[q];
                    acc1[q] += a1 * vv[q];
                }
            }
            __syncthreads();
        }
        // epilogue: multiply by gate, store in place over the gate half of hv
        {
            size_t r0 = rowg + i2;
            size_t r1 = rowg + i2 + 8;
            u16* g0p = hv + r0 * 4096 + 2048 + ec + e8;
            u16* g1p = hv + r1 * 4096 + 2048 + ec + e8;
#pragma unroll
            for (int q = 0; q < 8; ++q) {
                float o0 = acc0[q] * b2f(g0p[q]);
                float o1 = acc1[q] * b2f(g1p[q]);
                g0p[q] = f2b(o0);
                g1p[q] = f2b(o1);
            }
        }
    }
}

// ---------- launch ----------
extern "C" void kernel_launch(void* const* d_in, const int* in_sizes, int n_in,
                              void* d_out, int out_size, void* d_ws, size_t ws_size,
                              hipStream_t stream) {
    const float* x = (const float*)d_in[0];
    const float* ln_w = (const float*)d_in[1];
    const float* ln_b = (const float*)d_in[2];
    const float* Wh = (const float*)d_in[3];
    const float* bh = (const float*)d_in[4];
    const float* Wqk = (const float*)d_in[5];
    const float* bqk = (const float*)d_in[6];
    const float* qk_w = (const float*)d_in[7];
    const float* qk_b = (const float*)d_in[8];
    const float* rel_table = (const float*)d_in[9];
    const float* Wout = (const float*)d_in[10];
    const float* bout = (const float*)d_in[11];
    float* out = (float*)d_out;

    char* ws = (char*)d_ws;
    u16* normed = (u16*)(ws);                 // 33,554,432 B (dead after GEMMs)
    u16* kvbuf  = (u16*)(ws);                 // aliases normed (32 MB)
    u16* hv     = (u16*)(ws + 33554432ull);   // 134,217,728 B (v | gate->gated)
    u16* qk     = (u16*)(ws + 167772160ull);  // 4,194,304 B
    // total = 171,966,464 B (~164 MiB)

    ln_kernel<<<16384, 256, 0, stream>>>(x, ln_w, ln_b, normed);
    gemm64<0><<<dim3(64, 256), 256, 0, stream>>>(normed, 1024, Wh, bh, nullptr, hv, 16384, 4096, 1024);
    gemm64<0><<<dim3(2, 256), 256, 0, stream>>>(normed, 1024, Wqk, bqk, nullptr, qk, 16384, 128, 1024);
    kv_kernel<<<dim3(64, 32), 256, 0, stream>>>(qk, hv, qk_w, qk_b, kvbuf);
    prefix_kernel<<<4096, 256, 0, stream>>>(kvbuf);
    attn_kernel<<<dim3(64, 16), 256, 0, stream>>>(qk, hv, kvbuf, qk_w, qk_b, rel_table);
    gemm64<1><<<dim3(16, 256), 256, 0, stream>>>(hv + 2048, 4096, Wout, bout, x, out, 16384, 1024, 2048);
}

// Round 5
// 1312.894 us; speedup vs baseline: 2.6963x; 2.6963x over previous
//
#include <hip/hip_runtime.h>
#include <hip/hip_bf16.h>

typedef unsigned short u16;
typedef short s8v __attribute__((ext_vector_type(8)));   // 8 bf16 as i16 (4 VGPRs)
typedef float f4v __attribute__((ext_vector_type(4)));   // MFMA 16x16 accumulator

// ---------- helpers ----------
__device__ __forceinline__ float b2f(u16 u) { return __uint_as_float(((unsigned)u) << 16); }
__device__ __forceinline__ u16 f2b(float f) {
    unsigned u = __float_as_uint(f);
    unsigned r = 0x7FFFu + ((u >> 16) & 1u);
    return (u16)((u + r) >> 16);
}
__device__ __forceinline__ float silu_f(float x) { return x / (1.0f + expf(-x)); }

__device__ __forceinline__ void gld16(const u16* g, u16* l) {
    __builtin_amdgcn_global_load_lds((const __attribute__((address_space(1))) unsigned*)g,
                                     (__attribute__((address_space(3))) unsigned*)l, 16, 0, 0);
}

// ---------- constants ----------
// DIM=1024, HID=2048, QK=128, G=256, NG=16, B=4, ROWS=16384
// I/O dtype: FP32. Intermediates: bf16 in ws.

// ---------- fp32 -> bf16 transpose (weights): out[n][k] = bf16(in[k][n]) ----------
__global__ __launch_bounds__(256) void convT_kernel(const float* __restrict__ in,
                                                    u16* __restrict__ out, int K, int N) {
    __shared__ float tile[32][33];
    int k0 = blockIdx.y * 32, n0 = blockIdx.x * 32;
    int t = threadIdx.x;
    int r = t >> 5, c = t & 31;
#pragma unroll
    for (int rr = r; rr < 32; rr += 8) tile[rr][c] = in[(size_t)(k0 + rr) * N + n0 + c];
    __syncthreads();
#pragma unroll
    for (int rr = r; rr < 32; rr += 8) out[(size_t)(n0 + rr) * K + k0 + c] = f2b(tile[c][rr]);
}

// ---------- LayerNorm: fp32 in -> bf16 out ----------
__global__ __launch_bounds__(256) void ln_kernel(const float* __restrict__ x,
                                                 const float* __restrict__ w,
                                                 const float* __restrict__ bsh,
                                                 u16* __restrict__ out) {
    int row = blockIdx.x, t = threadIdx.x;
    const float* xr = x + (size_t)row * 1024;
    float4 u = *reinterpret_cast<const float4*>(xr + t * 4);
    float s = u.x + u.y + u.z + u.w;
    float s2 = u.x * u.x + u.y * u.y + u.z * u.z + u.w * u.w;
#pragma unroll
    for (int o = 32; o; o >>= 1) {
        s += __shfl_down(s, o, 64);
        s2 += __shfl_down(s2, o, 64);
    }
    __shared__ float rs[4], rs2[4];
    int wid = t >> 6;
    if ((t & 63) == 0) { rs[wid] = s; rs2[wid] = s2; }
    __syncthreads();
    float S = rs[0] + rs[1] + rs[2] + rs[3];
    float S2 = rs2[0] + rs2[1] + rs2[2] + rs2[3];
    float mu = S * (1.0f / 1024.0f);
    float var = S2 * (1.0f / 1024.0f) - mu * mu;
    float rinv = rsqrtf(var + 1e-5f);
    float4 uw = *reinterpret_cast<const float4*>(w + t * 4);
    float4 ub = *reinterpret_cast<const float4*>(bsh + t * 4);
    ushort4 o;
    o.x = f2b((u.x - mu) * rinv * uw.x + ub.x);
    o.y = f2b((u.y - mu) * rinv * uw.y + ub.y);
    o.z = f2b((u.z - mu) * rinv * uw.z + ub.z);
    o.w = f2b((u.w - mu) * rinv * uw.w + ub.w);
    *reinterpret_cast<ushort4*>(out + (size_t)row * 1024 + t * 4) = o;
}

// ---------- MFMA GEMM: C[M,N] = epi(A[M,K](bf16,lda) @ Bt[N,K](bf16,ldb)^T + bias) ----------
// 128x128 tile, BK=64, 4 waves (2x2), wave = 64x64 = 4x4 MFMA 16x16x32.
// LDS XOR-swizzle: row r chunk slot s holds logical k-chunk s^(r&7) -> conflict-free
// ds_read_b128 AND contiguous lane*16 dest for global_load_lds (can't pad).
// MODE 0: silu(acc+bias) -> bf16 C      MODE 1: acc+bias+resid -> fp32 C
template <int MODE>
__global__ __launch_bounds__(256) void gemm_mfma(const u16* __restrict__ A, int lda,
                                                 const u16* __restrict__ Bt, int ldb,
                                                 const float* __restrict__ bias,
                                                 const float* __restrict__ resid,
                                                 void* __restrict__ Cv,
                                                 int Nn, int K) {
    __shared__ __align__(16) u16 Al[128 * 64];
    __shared__ __align__(16) u16 Bl[128 * 64];
    const int t = threadIdx.x;
    const int lane = t & 63, w = t >> 6;
    const int wr = w >> 1, wc = w & 1;
    const int l15 = lane & 15, quad = lane >> 4, l7 = lane & 7;
    const int m0 = blockIdx.y * 128, n0 = blockIdx.x * 128;

    // staging source pointers (global), dest = lane-contiguous LDS
    const u16* ga[4];
    const u16* gb[4];
    const int sr = t >> 3, ss = t & 7;
#pragma unroll
    for (int i = 0; i < 4; ++i) {
        int r = i * 32 + sr;
        int q = ss ^ (r & 7);
        ga[i] = A + (size_t)(m0 + r) * lda + q * 8;
        gb[i] = Bt + (size_t)(n0 + r) * ldb + q * 8;
    }

    f4v acc[4][4] = {};

    for (int k0 = 0; k0 < K; k0 += 64) {
#pragma unroll
        for (int i = 0; i < 4; ++i) {
            gld16(ga[i] + k0, Al + i * 2048 + t * 8);
            gld16(gb[i] + k0, Bl + i * 2048 + t * 8);
        }
        __syncthreads();   // drains vmcnt (global_load_lds) + orders LDS
#pragma unroll
        for (int ks = 0; ks < 2; ++ks) {
            s8v af[4], bf[4];
            int cch = ((ks * 4 + quad) ^ l7) * 8;
#pragma unroll
            for (int mi = 0; mi < 4; ++mi) {
                int ra = wr * 64 + mi * 16 + l15;
                af[mi] = *(const s8v*)(Al + ra * 64 + cch);
            }
#pragma unroll
            for (int ni = 0; ni < 4; ++ni) {
                int rb = wc * 64 + ni * 16 + l15;
                bf[ni] = *(const s8v*)(Bl + rb * 64 + cch);
            }
#pragma unroll
            for (int mi = 0; mi < 4; ++mi)
#pragma unroll
                for (int ni = 0; ni < 4; ++ni)
                    acc[mi][ni] = __builtin_amdgcn_mfma_f32_16x16x32_bf16(af[mi], bf[ni], acc[mi][ni], 0, 0, 0);
        }
        __syncthreads();   // protect LDS from next stage
    }

    // epilogue: C/D frag mapping col=lane&15, row=quad*4+reg
#pragma unroll
    for (int ni = 0; ni < 4; ++ni) {
        int n = n0 + wc * 64 + ni * 16 + l15;
        float bs = bias[n];
#pragma unroll
        for (int mi = 0; mi < 4; ++mi) {
#pragma unroll
            for (int reg = 0; reg < 4; ++reg) {
                int m = m0 + wr * 64 + mi * 16 + quad * 4 + reg;
                float v = acc[mi][ni][reg] + bs;
                if (MODE == 0) {
                    ((u16*)Cv)[(size_t)m * Nn + n] = f2b(silu_f(v));
                } else {
                    ((float*)Cv)[(size_t)m * Nn + n] = v + resid[(size_t)m * Nn + n];
                }
            }
        }
    }
}

// ---------- small tiled GEMM (qk projection): bf16 A, fp32 B, silu -> bf16 ----------
__global__ __launch_bounds__(256) void gemm64_silu(const u16* __restrict__ A, int lda,
                                                   const float* __restrict__ Bm,
                                                   const float* __restrict__ bias,
                                                   u16* __restrict__ C,
                                                   int Nn, int K) {
    __shared__ float As[16][64];
    __shared__ float Bs[16][64];
    const int t = threadIdx.x;
    const int tx = t & 15, ty = t >> 4;
    const int m0 = blockIdx.y * 64, n0 = blockIdx.x * 64;
    float acc[4][4] = {};

    const int ar = t >> 2, ac = (t & 3) * 4;
    const int br = t >> 4, bc = (t & 15) * 4;
    const u16* aptr = A + (size_t)(m0 + ar) * lda + ac;
    const float* bptr = Bm + (size_t)br * Nn + n0 + bc;

    for (int k0 = 0; k0 < K; k0 += 16) {
        ushort4 ua = *reinterpret_cast<const ushort4*>(aptr + k0);
        float4 ub = *reinterpret_cast<const float4*>(bptr + (size_t)k0 * Nn);
        As[ac + 0][ar] = b2f(ua.x);
        As[ac + 1][ar] = b2f(ua.y);
        As[ac + 2][ar] = b2f(ua.z);
        As[ac + 3][ar] = b2f(ua.w);
        Bs[br][bc + 0] = ub.x;
        Bs[br][bc + 1] = ub.y;
        Bs[br][bc + 2] = ub.z;
        Bs[br][bc + 3] = ub.w;
        __syncthreads();
#pragma unroll
        for (int kk = 0; kk < 16; ++kk) {
            float4 a = *reinterpret_cast<const float4*>(&As[kk][ty * 4]);
            float4 b = *reinterpret_cast<const float4*>(&Bs[kk][tx * 4]);
            acc[0][0] += a.x * b.x; acc[0][1] += a.x * b.y; acc[0][2] += a.x * b.z; acc[0][3] += a.x * b.w;
            acc[1][0] += a.y * b.x; acc[1][1] += a.y * b.y; acc[1][2] += a.y * b.z; acc[1][3] += a.y * b.w;
            acc[2][0] += a.z * b.x; acc[2][1] += a.z * b.y; acc[2][2] += a.z * b.z; acc[2][3] += a.z * b.w;
            acc[3][0] += a.w * b.x; acc[3][1] += a.w * b.y; acc[3][2] += a.w * b.z; acc[3][3] += a.w * b.w;
        }
        __syncthreads();
    }
#pragma unroll
    for (int i = 0; i < 4; ++i) {
        int m = m0 + ty * 4 + i;
#pragma unroll
        for (int j = 0; j < 4; ++j) {
            int n = n0 + tx * 4 + j;
            C[(size_t)m * Nn + n] = f2b(silu_f(acc[i][j] + bias[n]));
        }
    }
}

// ---------- per-group kv: kv[bg][d][e] = (1/256) * sum_n lin_k[n][d] * v[n][e] ----------
__global__ __launch_bounds__(256) void kv_kernel(const u16* __restrict__ qk,
                                                 const u16* __restrict__ hv,
                                                 const float* __restrict__ qk_w,
                                                 const float* __restrict__ qk_b,
                                                 u16* __restrict__ kvbuf) {
    __shared__ float ks[16][128];
    __shared__ float vs[16][64];
    __shared__ float kw[128], kb[128];
    int t = threadIdx.x;
    int bg = blockIdx.x, et = blockIdx.y;
    if (t < 128) {
        kw[t] = qk_w[3 * 128 + t];
        kb[t] = qk_b[3 * 128 + t];
    }
    __syncthreads();
    int d0 = (t >> 3) * 4;
    int e0 = (t & 7) * 8;
    float acc[4][8] = {};
    int rowbase = bg * 256;
    for (int n0 = 0; n0 < 256; n0 += 16) {
        {
            int r = t >> 4, c = (t & 15) * 8;
            const u16* p = qk + (size_t)(rowbase + n0 + r) * 128 + c;
#pragma unroll
            for (int q = 0; q < 2; ++q) {
                ushort4 u = *reinterpret_cast<const ushort4*>(p + q * 4);
                int cc = c + q * 4;
                ks[r][cc + 0] = b2f(u.x) * kw[cc + 0] + kb[cc + 0];
                ks[r][cc + 1] = b2f(u.y) * kw[cc + 1] + kb[cc + 1];
                ks[r][cc + 2] = b2f(u.z) * kw[cc + 2] + kb[cc + 2];
                ks[r][cc + 3] = b2f(u.w) * kw[cc + 3] + kb[cc + 3];
            }
        }
        {
            int r = t >> 4, c = (t & 15) * 4;
            const u16* p = hv + (size_t)(rowbase + n0 + r) * 4096 + et * 64 + c;
            ushort4 u = *reinterpret_cast<const ushort4*>(p);
            vs[r][c + 0] = b2f(u.x);
            vs[r][c + 1] = b2f(u.y);
            vs[r][c + 2] = b2f(u.z);
            vs[r][c + 3] = b2f(u.w);
        }
        __syncthreads();
#pragma unroll
        for (int kk = 0; kk < 16; ++kk) {
            float4 kf = *reinterpret_cast<const float4*>(&ks[kk][d0]);
            float4 va = *reinterpret_cast<const float4*>(&vs[kk][e0]);
            float4 vb = *reinterpret_cast<const float4*>(&vs[kk][e0 + 4]);
            float kfv[4] = {kf.x, kf.y, kf.z, kf.w};
            float vv[8] = {va.x, va.y, va.z, va.w, vb.x, vb.y, vb.z, vb.w};
#pragma unroll
            for (int i = 0; i < 4; ++i)
#pragma unroll
                for (int j = 0; j < 8; ++j) acc[i][j] += kfv[i] * vv[j];
        }
        __syncthreads();
    }
#pragma unroll
    for (int i = 0; i < 4; ++i)
#pragma unroll
        for (int j = 0; j < 8; ++j) {
            size_t idx = ((size_t)bg * 128 + d0 + i) * 2048 + et * 64 + e0 + j;
            kvbuf[idx] = f2b(acc[i][j] * (1.0f / 256.0f));
        }
}

// ---------- shifted cumsum over groups (in-place) ----------
__global__ __launch_bounds__(256) void prefix_kernel(u16* __restrict__ kvbuf) {
    size_t tid = (size_t)blockIdx.x * 256 + threadIdx.x;  // 1,048,576
    int e = (int)(tid & 2047);
    int d = (int)((tid >> 11) & 127);
    int b = (int)(tid >> 18);
    size_t base = ((size_t)b * 16 * 128 + d) * 2048 + e;
    const size_t gs = 128 * 2048;
    float vals[16];
#pragma unroll
    for (int g = 0; g < 16; ++g) vals[g] = b2f(kvbuf[base + (size_t)g * gs]);
    float s = 0.0f;
#pragma unroll
    for (int g = 0; g < 16; ++g) {
        kvbuf[base + (size_t)g * gs] = f2b(s);
        s += vals[g];
    }
}

// ---------- attention: per (group, 16-row i-tile) ----------
// Writes the gated output IN PLACE into the gate half of hv (cols 2048..4095).
__global__ __launch_bounds__(256) void attn_kernel(const u16* __restrict__ qk,
                                                   u16* __restrict__ hv,
                                                   const u16* __restrict__ kvbuf,
                                                   const float* __restrict__ qk_w,
                                                   const float* __restrict__ qk_b,
                                                   const float* __restrict__ rel_table) {
    __shared__ float qq[16][128];
    __shared__ float lq[16][128];
    __shared__ float attnS[16][256];
    __shared__ float stage[4096];
    __shared__ float biasn[256];
    __shared__ float w0[128], b0[128], w1[128], b1[128], w2[128], b2v[128];
    int t = threadIdx.x;
    int bg = blockIdx.x, it = blockIdx.y;

    if (t < 128) {
        w0[t] = qk_w[t];        b0[t] = qk_b[t];
        w1[t] = qk_w[128 + t];  b1[t] = qk_b[128 + t];
        w2[t] = qk_w[256 + t];  b2v[t] = qk_b[256 + t];
    }
    {
        int n = t;
        int bucket;
        if (n < 16) bucket = n;
        else {
            float v = logf((float)n / 16.0f) / 2.0794415416798357f * 16.0f;
            int vl = 16 + (int)v;
            bucket = vl > 31 ? 31 : vl;
        }
        biasn[n] = rel_table[bucket] * 11.313708498984761f;
    }
    __syncthreads();

    {
        int r = t >> 4, c = (t & 15) * 8;
        const u16* p = qk + (size_t)(bg * 256 + it * 16 + r) * 128 + c;
#pragma unroll
        for (int q = 0; q < 2; ++q) {
            ushort4 u = *reinterpret_cast<const ushort4*>(p + q * 4);
            float f[4] = {b2f(u.x), b2f(u.y), b2f(u.z), b2f(u.w)};
#pragma unroll
            for (int k = 0; k < 4; ++k) {
                int cc = c + q * 4 + k;
                qq[r][cc] = f[k] * w0[cc] + b0[cc];
                lq[r][cc] = f[k] * w1[cc] + b1[cc];
            }
        }
    }
    __syncthreads();

    int jmax = it * 16 + 15;

    // Phase A: attn scores
    for (int j0 = 0; j0 <= jmax; j0 += 32) {
        {
            int r = t >> 3, c = (t & 7) * 16;
            const u16* p = qk + (size_t)(bg * 256 + j0 + r) * 128 + c;
#pragma unroll
            for (int q = 0; q < 4; ++q) {
                ushort4 u = *reinterpret_cast<const ushort4*>(p + q * 4);
                float f[4] = {b2f(u.x), b2f(u.y), b2f(u.z), b2f(u.w)};
#pragma unroll
                for (int k = 0; k < 4; ++k) {
                    int cc = c + q * 4 + k;
                    stage[r * 128 + cc] = f[k] * w2[cc] + b2v[cc];
                }
            }
        }
        __syncthreads();
        int i = t >> 4;
        int gi = it * 16 + i;
#pragma unroll
        for (int u2 = 0; u2 < 2; ++u2) {
            int j = (t & 15) * 2 + u2;
            int gj = j0 + j;
            float dot = 0.0f;
            const float* qrow = &qq[i][0];
            const float* krow = &stage[j * 128];
#pragma unroll
            for (int c = 0; c < 128; c += 4) {
                float4 qa = *reinterpret_cast<const float4*>(qrow + c);
                float4 ka = *reinterpret_cast<const float4*>(krow + c);
                dot += qa.x * ka.x + qa.y * ka.y + qa.z * ka.z + qa.w * ka.w;
            }
            float aval = 0.0f;
            if (gj <= gi) {
                float sv = dot * (1.0f / 256.0f) + biasn[gi - gj];
                sv = fmaxf(sv, 0.0f);
                aval = sv * sv;
            }
            attnS[i][j0 + j] = aval;
        }
        __syncthreads();  // stage[] reused next iter / Phase B
    }

    // Phase B: out = attn @ v + lin_q @ kvpref, times gate
    int i2 = t >> 5;
    int e8 = (t & 31) * 8;
    size_t rowg = (size_t)bg * 256 + it * 16;
    for (int ec = 0; ec < 2048; ec += 256) {
        float acc0[8] = {};
        float acc1[8] = {};
        for (int j0 = 0; j0 <= jmax; j0 += 16) {
            {
                int r = t >> 4, c = (t & 15) * 16;
                const u16* p = hv + (size_t)(bg * 256 + j0 + r) * 4096 + ec + c;
#pragma unroll
                for (int q = 0; q < 4; ++q) {
                    ushort4 u = *reinterpret_cast<const ushort4*>(p + q * 4);
                    stage[r * 256 + c + q * 4 + 0] = b2f(u.x);
                    stage[r * 256 + c + q * 4 + 1] = b2f(u.y);
                    stage[r * 256 + c + q * 4 + 2] = b2f(u.z);
                    stage[r * 256 + c + q * 4 + 3] = b2f(u.w);
                }
            }
            __syncthreads();
#pragma unroll
            for (int j = 0; j < 16; ++j) {
                float a0 = attnS[i2][j0 + j];
                float a1 = attnS[i2 + 8][j0 + j];
                const float* vr = &stage[j * 256 + e8];
                float4 p0 = *reinterpret_cast<const float4*>(vr);
                float4 p1 = *reinterpret_cast<const float4*>(vr + 4);
                float vv[8] = {p0.x, p0.y, p0.z, p0.w, p1.x, p1.y, p1.z, p1.w};
#pragma unroll
                for (int q = 0; q < 8; ++q) {
                    acc0[q] += a0 * vv[q];
                    acc1[q] += a1 * vv[q];
                }
            }
            __syncthreads();
        }
        for (int d0 = 0; d0 < 128; d0 += 16) {
            {
                int r = t >> 4, c = (t & 15) * 16;
                const u16* p = kvbuf + ((size_t)bg * 128 + d0 + r) * 2048 + ec + c;
#pragma unroll
                for (int q = 0; q < 4; ++q) {
                    ushort4 u = *reinterpret_cast<const ushort4*>(p + q * 4);
                    stage[r * 256 + c + q * 4 + 0] = b2f(u.x);
                    stage[r * 256 + c + q * 4 + 1] = b2f(u.y);
                    stage[r * 256 + c + q * 4 + 2] = b2f(u.z);
                    stage[r * 256 + c + q * 4 + 3] = b2f(u.w);
                }
            }
            __syncthreads();
#pragma unroll
            for (int j = 0; j < 16; ++j) {
                float a0 = lq[i2][d0 + j];
                float a1 = lq[i2 + 8][d0 + j];
                const float* vr = &stage[j * 256 + e8];
                float4 p0 = *reinterpret_cast<const float4*>(vr);
                float4 p1 = *reinterpret_cast<const float4*>(vr + 4);
                float vv[8] = {p0.x, p0.y, p0.z, p0.w, p1.x, p1.y, p1.z, p1.w};
#pragma unroll
                for (int q = 0; q < 8; ++q) {
                    acc0[q] += a0 * vv[q];
                    acc1[q] += a1 * vv[q];
                }
            }
            __syncthreads();
        }
        {
            size_t r0 = rowg + i2;
            size_t r1 = rowg + i2 + 8;
            u16* g0p = hv + r0 * 4096 + 2048 + ec + e8;
            u16* g1p = hv + r1 * 4096 + 2048 + ec + e8;
#pragma unroll
            for (int q = 0; q < 8; ++q) {
                float o0 = acc0[q] * b2f(g0p[q]);
                float o1 = acc1[q] * b2f(g1p[q]);
                g0p[q] = f2b(o0);
                g1p[q] = f2b(o1);
            }
        }
    }
}

// ---------- launch ----------
extern "C" void kernel_launch(void* const* d_in, const int* in_sizes, int n_in,
                              void* d_out, int out_size, void* d_ws, size_t ws_size,
                              hipStream_t stream) {
    const float* x = (const float*)d_in[0];
    const float* ln_w = (const float*)d_in[1];
    const float* ln_b = (const float*)d_in[2];
    const float* Wh = (const float*)d_in[3];
    const float* bh = (const float*)d_in[4];
    const float* Wqk = (const float*)d_in[5];
    const float* bqk = (const float*)d_in[6];
    const float* qk_w = (const float*)d_in[7];
    const float* qk_b = (const float*)d_in[8];
    const float* rel_table = (const float*)d_in[9];
    const float* Wout = (const float*)d_in[10];
    const float* bout = (const float*)d_in[11];
    float* out = (float*)d_out;

    char* ws = (char*)d_ws;
    u16* normed = (u16*)(ws);                  // 32 MB (dead after projections)
    u16* kvbuf  = (u16*)(ws);                  // aliases normed
    u16* hv     = (u16*)(ws + 33554432ull);    // 128 MB (v | gate->gated)
    u16* qk     = (u16*)(ws + 167772160ull);   // 4 MB
    u16* WhT    = (u16*)(ws + 171966464ull);   // 8 MB  [4096][1024] bf16
    u16* WoutT  = (u16*)(ws + 180355072ull);   // 4 MB  [1024][2048] bf16
    // total = 184,549,376 B (~176 MiB)

    convT_kernel<<<dim3(128, 32), 256, 0, stream>>>(Wh, WhT, 1024, 4096);
    convT_kernel<<<dim3(32, 64), 256, 0, stream>>>(Wout, WoutT, 2048, 1024);
    ln_kernel<<<16384, 256, 0, stream>>>(x, ln_w, ln_b, normed);
    gemm_mfma<0><<<dim3(32, 128), 256, 0, stream>>>(normed, 1024, WhT, 1024, bh, nullptr, hv, 4096, 1024);
    gemm64_silu<<<dim3(2, 256), 256, 0, stream>>>(normed, 1024, Wqk, bqk, qk, 128, 1024);
    kv_kernel<<<dim3(64, 32), 256, 0, stream>>>(qk, hv, qk_w, qk_b, kvbuf);
    prefix_kernel<<<4096, 256, 0, stream>>>(kvbuf);
    attn_kernel<<<dim3(64, 16), 256, 0, stream>>>(qk, hv, kvbuf, qk_w, qk_b, rel_table);
    gemm_mfma<1><<<dim3(8, 128), 256, 0, stream>>>(hv + 2048, 4096, WoutT, 2048, bout, x, out, 1024, 2048);
}

// Round 6
// 780.104 us; speedup vs baseline: 4.5379x; 1.6830x over previous
//
#include <hip/hip_runtime.h>
#include <hip/hip_bf16.h>

typedef unsigned short u16;
typedef short s8v __attribute__((ext_vector_type(8)));   // 8 bf16 as i16 (4 VGPRs)
typedef float f4v __attribute__((ext_vector_type(4)));   // MFMA 16x16 accumulator

// ---------- helpers ----------
__device__ __forceinline__ float b2f(u16 u) { return __uint_as_float(((unsigned)u) << 16); }
__device__ __forceinline__ u16 f2b(float f) {
    unsigned u = __float_as_uint(f);
    unsigned r = 0x7FFFu + ((u >> 16) & 1u);
    return (u16)((u + r) >> 16);
}
__device__ __forceinline__ float silu_f(float x) { return x / (1.0f + expf(-x)); }

__device__ __forceinline__ void gld16(const u16* g, u16* l) {
    __builtin_amdgcn_global_load_lds((const __attribute__((address_space(1))) unsigned*)g,
                                     (__attribute__((address_space(3))) unsigned*)l, 16, 0, 0);
}

// shared MFMA inner block: BK=64 staged in Al/Bl (XOR-swizzled), 4x4 16x16 tiles/wave
__device__ __forceinline__ void mfma_block(const u16* Al, const u16* Bl, f4v acc[4][4],
                                           int wr, int wc, int l15, int quad, int l7) {
#pragma unroll
    for (int ks = 0; ks < 2; ++ks) {
        s8v af[4], bf[4];
        int cch = ((ks * 4 + quad) ^ l7) * 8;
#pragma unroll
        for (int mi = 0; mi < 4; ++mi)
            af[mi] = *(const s8v*)(Al + (wr * 64 + mi * 16 + l15) * 64 + cch);
#pragma unroll
        for (int ni = 0; ni < 4; ++ni)
            bf[ni] = *(const s8v*)(Bl + (wc * 64 + ni * 16 + l15) * 64 + cch);
#pragma unroll
        for (int mi = 0; mi < 4; ++mi)
#pragma unroll
            for (int ni = 0; ni < 4; ++ni)
                acc[mi][ni] = __builtin_amdgcn_mfma_f32_16x16x32_bf16(af[mi], bf[ni], acc[mi][ni], 0, 0, 0);
    }
}

// ---------- constants ----------
// DIM=1024, HID=2048, QK=128, G=256, NG=16, B=4, ROWS=16384
// I/O fp32; intermediates bf16. heads: 0=quad_q 1=lin_q 2=quad_k 3=lin_k

// ---------- fp32 -> bf16 transpose (weights) ----------
__global__ __launch_bounds__(256) void convT_kernel(const float* __restrict__ in,
                                                    u16* __restrict__ out, int K, int N) {
    __shared__ float tile[32][33];
    int k0 = blockIdx.y * 32, n0 = blockIdx.x * 32;
    int t = threadIdx.x;
    int r = t >> 5, c = t & 31;
#pragma unroll
    for (int rr = r; rr < 32; rr += 8) tile[rr][c] = in[(size_t)(k0 + rr) * N + n0 + c];
    __syncthreads();
#pragma unroll
    for (int rr = r; rr < 32; rr += 8) out[(size_t)(n0 + rr) * K + k0 + c] = f2b(tile[c][rr]);
}

// ---------- LayerNorm: fp32 in -> bf16 out ----------
__global__ __launch_bounds__(256) void ln_kernel(const float* __restrict__ x,
                                                 const float* __restrict__ w,
                                                 const float* __restrict__ bsh,
                                                 u16* __restrict__ out) {
    int row = blockIdx.x, t = threadIdx.x;
    const float* xr = x + (size_t)row * 1024;
    float4 u = *reinterpret_cast<const float4*>(xr + t * 4);
    float s = u.x + u.y + u.z + u.w;
    float s2 = u.x * u.x + u.y * u.y + u.z * u.z + u.w * u.w;
#pragma unroll
    for (int o = 32; o; o >>= 1) {
        s += __shfl_down(s, o, 64);
        s2 += __shfl_down(s2, o, 64);
    }
    __shared__ float rs[4], rs2[4];
    int wid = t >> 6;
    if ((t & 63) == 0) { rs[wid] = s; rs2[wid] = s2; }
    __syncthreads();
    float S = rs[0] + rs[1] + rs[2] + rs[3];
    float S2 = rs2[0] + rs2[1] + rs2[2] + rs2[3];
    float mu = S * (1.0f / 1024.0f);
    float var = S2 * (1.0f / 1024.0f) - mu * mu;
    float rinv = rsqrtf(var + 1e-5f);
    float4 uw = *reinterpret_cast<const float4*>(w + t * 4);
    float4 ub = *reinterpret_cast<const float4*>(bsh + t * 4);
    ushort4 o;
    o.x = f2b((u.x - mu) * rinv * uw.x + ub.x);
    o.y = f2b((u.y - mu) * rinv * uw.y + ub.y);
    o.z = f2b((u.z - mu) * rinv * uw.z + ub.z);
    o.w = f2b((u.w - mu) * rinv * uw.w + ub.w);
    *reinterpret_cast<ushort4*>(out + (size_t)row * 1024 + t * 4) = o;
}

// ---------- Wh MFMA GEMM: silu(normed @ WhT^T + bh) -> vT (cols<2048) | gate (cols>=2048) ----------
__global__ __launch_bounds__(256) void gemm_hv(const u16* __restrict__ A,
                                               const u16* __restrict__ Bt,
                                               const float* __restrict__ bias,
                                               u16* __restrict__ vT,
                                               u16* __restrict__ gate) {
    __shared__ __align__(16) u16 Al[128 * 64];
    __shared__ __align__(16) u16 Bl[128 * 64];
    const int t = threadIdx.x;
    const int lane = t & 63, w = t >> 6;
    const int wr = w >> 1, wc = w & 1;
    const int l15 = lane & 15, quad = lane >> 4, l7 = lane & 7;
    const int m0 = blockIdx.y * 128, n0 = blockIdx.x * 128;
    const int sr = t >> 3, ss = t & 7;

    f4v acc[4][4] = {};
    for (int k0 = 0; k0 < 1024; k0 += 64) {
#pragma unroll
        for (int i = 0; i < 4; ++i) {
            int r = i * 32 + sr;
            int q = ss ^ (r & 7);
            gld16(A + (size_t)(m0 + r) * 1024 + q * 8 + k0, Al + i * 2048 + t * 8);
            gld16(Bt + (size_t)(n0 + r) * 1024 + q * 8 + k0, Bl + i * 2048 + t * 8);
        }
        __syncthreads();
        mfma_block(Al, Bl, acc, wr, wc, l15, quad, l7);
        __syncthreads();
    }
    const bool isV = (n0 < 2048);
    const int bg = m0 >> 8;
#pragma unroll
    for (int ni = 0; ni < 4; ++ni) {
        int n = n0 + wc * 64 + ni * 16 + l15;
        float bs = bias[n];
#pragma unroll
        for (int mi = 0; mi < 4; ++mi) {
#pragma unroll
            for (int reg = 0; reg < 4; ++reg) {
                int m = m0 + wr * 64 + mi * 16 + quad * 4 + reg;
                u16 v = f2b(silu_f(acc[mi][ni][reg] + bs));
                if (isV) {
                    vT[((size_t)bg * 2048 + n) * 256 + (m & 255)] = v;
                } else {
                    gate[(size_t)m * 2048 + (n - 2048)] = v;
                }
            }
        }
    }
}

// ---------- final MFMA GEMM: gated @ WoutT^T + bout + x -> fp32 out ----------
__global__ __launch_bounds__(256) void gemm_out(const u16* __restrict__ A,
                                                const u16* __restrict__ Bt,
                                                const float* __restrict__ bias,
                                                const float* __restrict__ resid,
                                                float* __restrict__ C) {
    __shared__ __align__(16) u16 Al[128 * 64];
    __shared__ __align__(16) u16 Bl[128 * 64];
    const int t = threadIdx.x;
    const int lane = t & 63, w = t >> 6;
    const int wr = w >> 1, wc = w & 1;
    const int l15 = lane & 15, quad = lane >> 4, l7 = lane & 7;
    const int m0 = blockIdx.y * 128, n0 = blockIdx.x * 128;
    const int sr = t >> 3, ss = t & 7;

    f4v acc[4][4] = {};
    for (int k0 = 0; k0 < 2048; k0 += 64) {
#pragma unroll
        for (int i = 0; i < 4; ++i) {
            int r = i * 32 + sr;
            int q = ss ^ (r & 7);
            gld16(A + (size_t)(m0 + r) * 2048 + q * 8 + k0, Al + i * 2048 + t * 8);
            gld16(Bt + (size_t)(n0 + r) * 2048 + q * 8 + k0, Bl + i * 2048 + t * 8);
        }
        __syncthreads();
        mfma_block(Al, Bl, acc, wr, wc, l15, quad, l7);
        __syncthreads();
    }
#pragma unroll
    for (int ni = 0; ni < 4; ++ni) {
        int n = n0 + wc * 64 + ni * 16 + l15;
        float bs = bias[n];
#pragma unroll
        for (int mi = 0; mi < 4; ++mi) {
#pragma unroll
            for (int reg = 0; reg < 4; ++reg) {
                int m = m0 + wr * 64 + mi * 16 + quad * 4 + reg;
                C[(size_t)m * 1024 + n] = acc[mi][ni][reg] + bs + resid[(size_t)m * 1024 + n];
            }
        }
    }
}

// ---------- small tiled GEMM (qk projection): bf16 A, fp32 B, silu -> bf16 ----------
__global__ __launch_bounds__(256) void gemm64_silu(const u16* __restrict__ A, int lda,
                                                   const float* __restrict__ Bm,
                                                   const float* __restrict__ bias,
                                                   u16* __restrict__ C,
                                                   int Nn, int K) {
    __shared__ float As[16][64];
    __shared__ float Bs[16][64];
    const int t = threadIdx.x;
    const int tx = t & 15, ty = t >> 4;
    const int m0 = blockIdx.y * 64, n0 = blockIdx.x * 64;
    float acc[4][4] = {};

    const int ar = t >> 2, ac = (t & 3) * 4;
    const int br = t >> 4, bc = (t & 15) * 4;
    const u16* aptr = A + (size_t)(m0 + ar) * lda + ac;
    const float* bptr = Bm + (size_t)br * Nn + n0 + bc;

    for (int k0 = 0; k0 < K; k0 += 16) {
        ushort4 ua = *reinterpret_cast<const ushort4*>(aptr + k0);
        float4 ub = *reinterpret_cast<const float4*>(bptr + (size_t)k0 * Nn);
        As[ac + 0][ar] = b2f(ua.x);
        As[ac + 1][ar] = b2f(ua.y);
        As[ac + 2][ar] = b2f(ua.z);
        As[ac + 3][ar] = b2f(ua.w);
        Bs[br][bc + 0] = ub.x;
        Bs[br][bc + 1] = ub.y;
        Bs[br][bc + 2] = ub.z;
        Bs[br][bc + 3] = ub.w;
        __syncthreads();
#pragma unroll
        for (int kk = 0; kk < 16; ++kk) {
            float4 a = *reinterpret_cast<const float4*>(&As[kk][ty * 4]);
            float4 b = *reinterpret_cast<const float4*>(&Bs[kk][tx * 4]);
            acc[0][0] += a.x * b.x; acc[0][1] += a.x * b.y; acc[0][2] += a.x * b.z; acc[0][3] += a.x * b.w;
            acc[1][0] += a.y * b.x; acc[1][1] += a.y * b.y; acc[1][2] += a.y * b.z; acc[1][3] += a.y * b.w;
            acc[2][0] += a.z * b.x; acc[2][1] += a.z * b.y; acc[2][2] += a.z * b.z; acc[2][3] += a.z * b.w;
            acc[3][0] += a.w * b.x; acc[3][1] += a.w * b.y; acc[3][2] += a.w * b.z; acc[3][3] += a.w * b.w;
        }
        __syncthreads();
    }
#pragma unroll
    for (int i = 0; i < 4; ++i) {
        int m = m0 + ty * 4 + i;
#pragma unroll
        for (int j = 0; j < 4; ++j) {
            int n = n0 + tx * 4 + j;
            C[(size_t)m * Nn + n] = f2b(silu_f(acc[i][j] + bias[n]));
        }
    }
}

// ---------- scores: Sbuf[bg][i][0..255] = relu^2(qq.kk^T/256 + t5bias, causal), [256..383] = lq ----------
__global__ __launch_bounds__(256) void scores_kernel(const u16* __restrict__ qk,
                                                     const float* __restrict__ qk_w,
                                                     const float* __restrict__ qk_b,
                                                     const float* __restrict__ rel_table,
                                                     u16* __restrict__ Sbuf) {
    __shared__ __align__(16) u16 qkl[256 * 128];   // raw qk rows for this group (64KB)
    __shared__ float biasn[256];
    __shared__ float w0[128], b0[128], w1[128], b1[128], w2[128], b2v[128];
    const int t = threadIdx.x;
    const int bg = blockIdx.x >> 1, mt = blockIdx.x & 1;
    const int lane = t & 63, w = t >> 6;
    const int wr = w >> 1, wc = w & 1;
    const int l15 = lane & 15, quad = lane >> 4;

    if (t < 128) {
        w0[t] = qk_w[t];        b0[t] = qk_b[t];
        w1[t] = qk_w[128 + t];  b1[t] = qk_b[128 + t];
        w2[t] = qk_w[256 + t];  b2v[t] = qk_b[256 + t];
    }
    {
        int n = t;
        int bucket;
        if (n < 16) bucket = n;
        else {
            float v = logf((float)n / 16.0f) / 2.0794415416798357f * 16.0f;
            int vl = 16 + (int)v;
            bucket = vl > 31 ? 31 : vl;
        }
        biasn[n] = rel_table[bucket] * 11.313708498984761f;
    }
    // stage all 256 rows x 128 cols of this group's qk
#pragma unroll
    for (int it = 0; it < 16; ++it) {
        int r = (t >> 4) + it * 16, c = (t & 15) * 8;
        *(s8v*)(qkl + r * 128 + c) = *(const s8v*)(qk + ((size_t)(bg * 256 + r)) * 128 + c);
    }
    __syncthreads();

    // wave tile: 64 m-rows x 128 n-cols; block: 128 rows (mt) x 256 cols
    f4v acc[4][8] = {};
#pragma unroll
    for (int kstep = 0; kstep < 4; ++kstep) {
        int kc = kstep * 32 + quad * 8;
        float w0f[8], b0f[8], w2f[8], b2f_[8];
#pragma unroll
        for (int j = 0; j < 8; ++j) {
            w0f[j] = w0[kc + j]; b0f[j] = b0[kc + j];
            w2f[j] = w2[kc + j]; b2f_[j] = b2v[kc + j];
        }
        s8v af[4];
#pragma unroll
        for (int mi = 0; mi < 4; ++mi) {
            int ra = mt * 128 + wr * 64 + mi * 16 + l15;
            s8v raw = *(const s8v*)(qkl + ra * 128 + kc);
#pragma unroll
            for (int j = 0; j < 8; ++j) af[mi][j] = (short)f2b(b2f((u16)raw[j]) * w0f[j] + b0f[j]);
        }
#pragma unroll
        for (int np = 0; np < 2; ++np) {
            s8v bf[4];
#pragma unroll
            for (int ni = 0; ni < 4; ++ni) {
                int rb = wc * 128 + (np * 4 + ni) * 16 + l15;
                s8v raw = *(const s8v*)(qkl + rb * 128 + kc);
#pragma unroll
                for (int j = 0; j < 8; ++j) bf[ni][j] = (short)f2b(b2f((u16)raw[j]) * w2f[j] + b2f_[j]);
            }
#pragma unroll
            for (int mi = 0; mi < 4; ++mi)
#pragma unroll
                for (int ni = 0; ni < 4; ++ni)
                    acc[mi][np * 4 + ni] = __builtin_amdgcn_mfma_f32_16x16x32_bf16(af[mi], bf[ni], acc[mi][np * 4 + ni], 0, 0, 0);
        }
    }
    // epilogue: bias + relu^2 + causal -> bf16 Sbuf
#pragma unroll
    for (int ni = 0; ni < 8; ++ni) {
        int gj = wc * 128 + ni * 16 + l15;
#pragma unroll
        for (int mi = 0; mi < 4; ++mi) {
#pragma unroll
            for (int reg = 0; reg < 4; ++reg) {
                int gi = mt * 128 + wr * 64 + mi * 16 + quad * 4 + reg;
                float aval = 0.0f;
                if (gj <= gi) {
                    float sv = acc[mi][ni][reg] * (1.0f / 256.0f) + biasn[gi - gj];
                    sv = fmaxf(sv, 0.0f);
                    aval = sv * sv;
                }
                Sbuf[((size_t)bg * 256 + gi) * 384 + gj] = f2b(aval);
            }
        }
    }
    // lq columns 256..383
#pragma unroll
    for (int it = 0; it < 8; ++it) {
        int i = mt * 128 + (t >> 4) + it * 16;
        int d = (t & 15) * 8;
        s8v raw = *(const s8v*)(qkl + i * 128 + d);
        u16* dst = Sbuf + ((size_t)bg * 256 + i) * 384 + 256 + d;
#pragma unroll
        for (int j = 0; j < 8; ++j)
            dst[j] = f2b(b2f((u16)raw[j]) * w1[d + j] + b1[d + j]);
    }
}

// ---------- per-group kvT[e][d] = (1/256) * sum_j lin_k[j][d] * v[j][e] ----------
__global__ __launch_bounds__(256) void kv_kernel(const u16* __restrict__ qk,
                                                 const u16* __restrict__ vT,
                                                 const float* __restrict__ qk_w,
                                                 const float* __restrict__ qk_b,
                                                 u16* __restrict__ kvT) {
    __shared__ float ks[16][128];
    __shared__ float vs[16][64];
    __shared__ float kw[128], kb[128];
    int t = threadIdx.x;
    int bg = blockIdx.x, et = blockIdx.y;
    if (t < 128) {
        kw[t] = qk_w[3 * 128 + t];
        kb[t] = qk_b[3 * 128 + t];
    }
    __syncthreads();
    int d0 = (t >> 3) * 4;
    int e0 = (t & 7) * 8;
    float acc[4][8] = {};
    int rowbase = bg * 256;
    for (int n0 = 0; n0 < 256; n0 += 16) {
        {
            int r = t >> 4, c = (t & 15) * 8;
            const u16* p = qk + (size_t)(rowbase + n0 + r) * 128 + c;
#pragma unroll
            for (int q = 0; q < 2; ++q) {
                ushort4 u = *reinterpret_cast<const ushort4*>(p + q * 4);
                int cc = c + q * 4;
                ks[r][cc + 0] = b2f(u.x) * kw[cc + 0] + kb[cc + 0];
                ks[r][cc + 1] = b2f(u.y) * kw[cc + 1] + kb[cc + 1];
                ks[r][cc + 2] = b2f(u.z) * kw[cc + 2] + kb[cc + 2];
                ks[r][cc + 3] = b2f(u.w) * kw[cc + 3] + kb[cc + 3];
            }
        }
        {
            int e = t >> 2, jq = t & 3;
            const u16* p = vT + ((size_t)bg * 2048 + et * 64 + e) * 256 + n0 + jq * 4;
            ushort4 u = *reinterpret_cast<const ushort4*>(p);
            vs[jq * 4 + 0][e] = b2f(u.x);
            vs[jq * 4 + 1][e] = b2f(u.y);
            vs[jq * 4 + 2][e] = b2f(u.z);
            vs[jq * 4 + 3][e] = b2f(u.w);
        }
        __syncthreads();
#pragma unroll
        for (int kk = 0; kk < 16; ++kk) {
            float4 kf = *reinterpret_cast<const float4*>(&ks[kk][d0]);
            float4 va = *reinterpret_cast<const float4*>(&vs[kk][e0]);
            float4 vb = *reinterpret_cast<const float4*>(&vs[kk][e0 + 4]);
            float kfv[4] = {kf.x, kf.y, kf.z, kf.w};
            float vv[8] = {va.x, va.y, va.z, va.w, vb.x, vb.y, vb.z, vb.w};
#pragma unroll
            for (int i = 0; i < 4; ++i)
#pragma unroll
                for (int j = 0; j < 8; ++j) acc[i][j] += kfv[i] * vv[j];
        }
        __syncthreads();
    }
#pragma unroll
    for (int i = 0; i < 4; ++i)
#pragma unroll
        for (int j = 0; j < 8; ++j) {
            size_t idx = ((size_t)bg * 2048 + et * 64 + e0 + j) * 128 + d0 + i;
            kvT[idx] = f2b(acc[i][j] * (1.0f / 256.0f));
        }
}

// ---------- shifted cumsum over groups (in-place, kvT layout [b][g][e][d]) ----------
__global__ __launch_bounds__(256) void prefix_kernel(u16* __restrict__ kvT) {
    size_t tid = (size_t)blockIdx.x * 256 + threadIdx.x;  // 1,048,576
    int d = (int)(tid & 127);
    int e = (int)((tid >> 7) & 2047);
    int b = (int)(tid >> 18);
    size_t base = ((size_t)(b * 16) * 2048 + e) * 128 + d;
    const size_t gs = 2048 * 128;
    float vals[16];
#pragma unroll
    for (int g = 0; g < 16; ++g) vals[g] = b2f(kvT[base + (size_t)g * gs]);
    float s = 0.0f;
#pragma unroll
    for (int g = 0; g < 16; ++g) {
        kvT[base + (size_t)g * gs] = f2b(s);
        s += vals[g];
    }
}

// ---------- attention GEMM: out = [S|lq] @ [v;kv], times gate, in place over gate ----------
__global__ __launch_bounds__(256) void attn_gemm(const u16* __restrict__ Sbuf,
                                                 const u16* __restrict__ vT,
                                                 const u16* __restrict__ kvT,
                                                 u16* __restrict__ gate) {
    __shared__ __align__(16) u16 Al[128 * 64];
    __shared__ __align__(16) u16 Bl[128 * 64];
    const int t = threadIdx.x;
    const int lane = t & 63, w = t >> 6;
    const int wr = w >> 1, wc = w & 1;
    const int l15 = lane & 15, quad = lane >> 4, l7 = lane & 7;
    const int bg = blockIdx.y >> 1, mt = blockIdx.y & 1;
    const int n0 = blockIdx.x * 128;   // e offset
    const int sr = t >> 3, ss = t & 7;

    const u16* Abase = Sbuf + ((size_t)bg * 256 + mt * 128) * 384;
    const u16* Bv = vT + (size_t)bg * 2048 * 256;
    const u16* Bk = kvT + (size_t)bg * 2048 * 128;

    f4v acc[4][4] = {};
    // phase 1: K=256 (S @ v)
    for (int k0 = 0; k0 < 256; k0 += 64) {
#pragma unroll
        for (int i = 0; i < 4; ++i) {
            int r = i * 32 + sr;
            int q = ss ^ (r & 7);
            gld16(Abase + (size_t)r * 384 + q * 8 + k0, Al + i * 2048 + t * 8);
            gld16(Bv + (size_t)(n0 + r) * 256 + q * 8 + k0, Bl + i * 2048 + t * 8);
        }
        __syncthreads();
        mfma_block(Al, Bl, acc, wr, wc, l15, quad, l7);
        __syncthreads();
    }
    // phase 2: K=128 (lq @ kv_pref)
    for (int k0 = 0; k0 < 128; k0 += 64) {
#pragma unroll
        for (int i = 0; i < 4; ++i) {
            int r = i * 32 + sr;
            int q = ss ^ (r & 7);
            gld16(Abase + (size_t)r * 384 + 256 + q * 8 + k0, Al + i * 2048 + t * 8);
            gld16(Bk + (size_t)(n0 + r) * 128 + q * 8 + k0, Bl + i * 2048 + t * 8);
        }
        __syncthreads();
        mfma_block(Al, Bl, acc, wr, wc, l15, quad, l7);
        __syncthreads();
    }
    // epilogue: multiply by gate, write gated in place
#pragma unroll
    for (int ni = 0; ni < 4; ++ni) {
        int e = n0 + wc * 64 + ni * 16 + l15;
#pragma unroll
        for (int mi = 0; mi < 4; ++mi) {
#pragma unroll
            for (int reg = 0; reg < 4; ++reg) {
                int gi = mt * 128 + wr * 64 + mi * 16 + quad * 4 + reg;
                u16* p = gate + ((size_t)bg * 256 + gi) * 2048 + e;
                *p = f2b(acc[mi][ni][reg] * b2f(*p));
            }
        }
    }
}

// ---------- launch ----------
extern "C" void kernel_launch(void* const* d_in, const int* in_sizes, int n_in,
                              void* d_out, int out_size, void* d_ws, size_t ws_size,
                              hipStream_t stream) {
    const float* x = (const float*)d_in[0];
    const float* ln_w = (const float*)d_in[1];
    const float* ln_b = (const float*)d_in[2];
    const float* Wh = (const float*)d_in[3];
    const float* bh = (const float*)d_in[4];
    const float* Wqk = (const float*)d_in[5];
    const float* bqk = (const float*)d_in[6];
    const float* qk_w = (const float*)d_in[7];
    const float* qk_b = (const float*)d_in[8];
    const float* rel_table = (const float*)d_in[9];
    const float* Wout = (const float*)d_in[10];
    const float* bout = (const float*)d_in[11];
    float* out = (float*)d_out;

    char* ws = (char*)d_ws;
    u16* normed = (u16*)(ws);                  // 32 MB (dead after projections)
    u16* kvT    = (u16*)(ws);                  // aliases normed: [64][2048][128] 32 MB
    u16* gate   = (u16*)(ws + 33554432ull);    // [16384][2048] 64 MB (gate -> gated)
    u16* vT     = (u16*)(ws + 100663296ull);   // [64][2048][256] 64 MB
    u16* qk     = (u16*)(ws + 167772160ull);   // 4 MB
    u16* WhT    = (u16*)(ws + 171966464ull);   // [4096][1024] 8 MB
    u16* WoutT  = (u16*)(ws + 180355072ull);   // [1024][2048] 4 MB
    u16* Sbuf   = (u16*)(ws + 184549376ull);   // [64][256][384] 12,582,912 B
    // total = 197,132,288 B (~188 MiB)

    convT_kernel<<<dim3(128, 32), 256, 0, stream>>>(Wh, WhT, 1024, 4096);
    convT_kernel<<<dim3(32, 64), 256, 0, stream>>>(Wout, WoutT, 2048, 1024);
    ln_kernel<<<16384, 256, 0, stream>>>(x, ln_w, ln_b, normed);
    gemm_hv<<<dim3(32, 128), 256, 0, stream>>>(normed, WhT, bh, vT, gate);
    gemm64_silu<<<dim3(2, 256), 256, 0, stream>>>(normed, 1024, Wqk, bqk, qk, 128, 1024);
    scores_kernel<<<128, 256, 0, stream>>>(qk, qk_w, qk_b, rel_table, Sbuf);
    kv_kernel<<<dim3(64, 32), 256, 0, stream>>>(qk, vT, qk_w, qk_b, kvT);
    prefix_kernel<<<4096, 256, 0, stream>>>(kvT);
    attn_gemm<<<dim3(16, 128), 256, 0, stream>>>(Sbuf, vT, kvT, gate);
    gemm_out<<<dim3(8, 128), 256, 0, stream>>>(gate, WoutT, bout, x, out);
}